// Round 1
// baseline (38.118 us; speedup 1.0000x reference)
//
#include <hip/hip_runtime.h>

// EqFrePBC: frequency-domain perturbation compensation.
// B=2, L=2048, N=2 modes, pairs = full 40x40 grid (n1,n2 in [-20,19]).
// Restructured: G[b,m,d] = sum_n xf[b,m,n]*conj(xf[b,(m-d)%L,n])
//               S2[b,l,d] = sum_{n1} w[n1,d] * G[b,(l-n1)%L,d]
//               delta_f[b,l,n] = sum_d S2[b,l,d] * xf[b,(l-d)%L,n]
// Bias is constant over freq -> IFFT puts it only at t=0, which is cropped.

#define L_FFT 2048
#define NB 2
#define NM 2
#define ND 40
#define CROP 20
#define LOUT 2008

__device__ __forceinline__ float2 cmul(float2 a, float2 b) {
    return make_float2(a.x*b.x - a.y*b.y, a.x*b.y + a.y*b.x);
}
__device__ __forceinline__ float2 cmulc(float2 a, float2 b) {  // a * conj(b)
    return make_float2(a.x*b.x + a.y*b.y, a.y*b.x - a.x*b.y);
}

// Radix-2 Stockham autosort FFT, 2048 points, 256 threads.
// SIGN=-1: forward DFT; SIGN=+1: inverse (unscaled).
template<int SIGN>
__device__ float2* fft2048(float2* bufA, float2* bufB, int tid) {
    float2* src = bufA;
    float2* dst = bufB;
    int m = 1;
    for (int stage = 0; stage < 11; ++stage) {
        __syncthreads();
        #pragma unroll
        for (int it = 0; it < 4; ++it) {
            int q = tid + it * 256;
            int k = q & (m - 1);
            int jm = q - k;                 // j*m, twiddle index
            float ang = (float)SIGN * 3.0679615757712823e-03f * (float)jm; // 2*pi/2048
            float sv, cv;
            sincosf(ang, &sv, &cv);
            float2 a = src[q];
            float2 b = src[q + 1024];
            float2 w = make_float2(cv, sv);
            float2 dif = make_float2(a.x - b.x, a.y - b.y);
            dst[2*jm + k]     = make_float2(a.x + b.x, a.y + b.y);
            dst[2*jm + k + m] = cmul(dif, w);
        }
        float2* t = src; src = dst; dst = t;
        m <<= 1;
    }
    __syncthreads();
    return src;   // 11 stages (odd) -> result in bufB
}

__global__ __launch_bounds__(256) void fft_fwd_kernel(const float* __restrict__ xr,
                                                      const float* __restrict__ xi,
                                                      float2* __restrict__ xf) {
    __shared__ float2 bufA[L_FFT];
    __shared__ float2 bufB[L_FFT];
    int bn = blockIdx.x;            // b*2 + n
    int b = bn >> 1, n = bn & 1;
    int tid = threadIdx.x;
    for (int t = tid; t < L_FFT; t += 256) {
        int gi = (b * L_FFT + t) * NM + n;
        bufA[t] = make_float2(xr[gi], xi[gi]);
    }
    float2* res = fft2048<-1>(bufA, bufB, tid);
    for (int f = tid; f < L_FFT; f += 256)
        xf[bn * L_FFT + f] = res[f];
}

__global__ __launch_bounds__(256) void g_kernel(const float2* __restrict__ xf,
                                                float2* __restrict__ G) {
    int idx = blockIdx.x * 256 + threadIdx.x;   // [b][d][m]
    if (idx >= NB * ND * L_FFT) return;
    int m = idx & (L_FFT - 1);
    int d = (idx >> 11) % ND;
    int b = idx / (ND * L_FFT);
    int dd = d - 20;
    int m2 = (m - dd) & (L_FFT - 1);
    const float2* x0 = xf + (b * 2 + 0) * L_FFT;
    const float2* x1 = xf + (b * 2 + 1) * L_FFT;
    float2 g0 = cmulc(x0[m], x0[m2]);
    float2 g1 = cmulc(x1[m], x1[m2]);
    G[idx] = make_float2(g0.x + g1.x, g0.y + g1.y);
}

__global__ __launch_bounds__(256) void s2_kernel(const float2* __restrict__ G,
                                                 const float* __restrict__ wr,
                                                 const float* __restrict__ wi,
                                                 float2* __restrict__ S2) {
    int idx = blockIdx.x * 256 + threadIdx.x;   // [b][d][l]
    if (idx >= NB * ND * L_FFT) return;
    int l = idx & (L_FFT - 1);
    int d = (idx >> 11) % ND;
    int b = idx / (ND * L_FFT);
    const float2* Gbd = G + (b * ND + d) * L_FFT;
    float2 acc = make_float2(0.f, 0.f);
    #pragma unroll
    for (int n1i = 0; n1i < 40; ++n1i) {
        int n1 = n1i - 20;
        float wxr = wr[n1i * 40 + d];
        float wxi = wi[n1i * 40 + d];
        float2 g = Gbd[(l - n1) & (L_FFT - 1)];
        acc.x += wxr * g.x - wxi * g.y;
        acc.y += wxr * g.y + wxi * g.x;
    }
    S2[idx] = acc;
}

__global__ __launch_bounds__(256) void deltaf_kernel(const float2* __restrict__ xf,
                                                     const float2* __restrict__ S2,
                                                     float2* __restrict__ dfreq) {
    int idx = blockIdx.x * 256 + threadIdx.x;   // [b][n][l]
    if (idx >= NB * NM * L_FFT) return;
    int l = idx & (L_FFT - 1);
    int n = (idx >> 11) & 1;
    int b = idx >> 12;
    const float2* xbn = xf + (b * 2 + n) * L_FFT;
    float2 acc = make_float2(0.f, 0.f);
    #pragma unroll
    for (int d = 0; d < 40; ++d) {
        int dd = d - 20;
        float2 s = S2[(b * ND + d) * L_FFT + l];
        float2 xv = xbn[(l - dd) & (L_FFT - 1)];
        acc.x += s.x * xv.x - s.y * xv.y;
        acc.y += s.x * xv.y + s.y * xv.x;
    }
    dfreq[idx] = acc;
}

__global__ __launch_bounds__(256) void ifft_out_kernel(const float2* __restrict__ dfreq,
                                                       const float* __restrict__ xr,
                                                       const float* __restrict__ xi,
                                                       const float* __restrict__ task,
                                                       float* __restrict__ out) {
    __shared__ float2 bufA[L_FFT];
    __shared__ float2 bufB[L_FFT];
    int bn = blockIdx.x;            // b*2 + n
    int b = bn >> 1, n = bn & 1;
    int tid = threadIdx.x;
    for (int t = tid; t < L_FFT; t += 256)
        bufA[t] = dfreq[bn * L_FFT + t];
    float2* res = fft2048<1>(bufA, bufB, tid);
    float P = 1e-3f * powf(10.f, task[b * 4] * 0.1f) * 0.5f;   // /N with N=2
    float scale = P * (1.0f / (float)L_FFT);                   // fold ifft 1/L
    for (int t = CROP + tid; t < L_FFT - CROP; t += 256) {
        int gi = (b * L_FFT + t) * NM + n;
        float2 d = res[t];
        int oi = ((b * LOUT + (t - CROP)) * NM + n) * 2;
        out[oi]     = xr[gi] + d.x * scale;
        out[oi + 1] = xi[gi] + d.y * scale;
    }
}

extern "C" void kernel_launch(void* const* d_in, const int* in_sizes, int n_in,
                              void* d_out, int out_size, void* d_ws, size_t ws_size,
                              hipStream_t stream) {
    const float* xr   = (const float*)d_in[0];
    const float* xi   = (const float*)d_in[1];
    const float* task = (const float*)d_in[2];
    const float* wr   = (const float*)d_in[3];
    const float* wi   = (const float*)d_in[4];
    // d_in[5], d_in[6]: fc_br / fc_bi -- bias lands only at t=0 after IFFT, cropped out.
    float* out = (float*)d_out;

    float2* ws    = (float2*)d_ws;
    float2* xf    = ws;                        // 8192 float2   [b][n][l]
    float2* G     = ws + 8192;                 // 163840 float2 [b][d][m]
    float2* S2    = ws + 8192 + 163840;        // 163840 float2 [b][d][l]
    float2* dfreq = G;                         // reuse G region [b][n][l]

    hipLaunchKernelGGL(fft_fwd_kernel, dim3(NB * NM), dim3(256), 0, stream, xr, xi, xf);
    hipLaunchKernelGGL(g_kernel,      dim3((NB * ND * L_FFT + 255) / 256), dim3(256), 0, stream, xf, G);
    hipLaunchKernelGGL(s2_kernel,     dim3((NB * ND * L_FFT + 255) / 256), dim3(256), 0, stream, G, wr, wi, S2);
    hipLaunchKernelGGL(deltaf_kernel, dim3((NB * NM * L_FFT + 255) / 256), dim3(256), 0, stream, xf, S2, dfreq);
    hipLaunchKernelGGL(ifft_out_kernel, dim3(NB * NM), dim3(256), 0, stream, dfreq, xr, xi, task, out);
}

// Round 2
// 30.954 us; speedup vs baseline: 1.2314x; 1.2314x over previous
//
#include <hip/hip_runtime.h>

// EqFrePBC: frequency-domain perturbation compensation.
// B=2, L=2048, N=2 modes, pairs = full 40x40 grid (n1,n2 in [-20,19]).
// Restructured: G[b,m,d] = sum_n xf[b,m,n]*conj(xf[b,(m-d)%L,n])
//               S2[b,d,l] = sum_{n1} w[n1,d] * G[b,(l-n1)%L,d]
//               dfreq[b,n,l] = sum_d S2[b,d,l] * xf[b,n,(l-(d-20))%L]
// Bias is constant over freq -> IFFT puts it only at t=0, cropped out.
// 3 kernels: fwd-FFT (4 blk) -> fused G+S2 (640 blk) -> deltaf+IFFT+epilogue (4 blk).

#define L_FFT 2048
#define NB 2
#define NM 2
#define ND 40
#define CROP 20
#define LOUT 2008

__device__ __forceinline__ float2 cmul(float2 a, float2 b) {
    return make_float2(a.x*b.x - a.y*b.y, a.x*b.y + a.y*b.x);
}
__device__ __forceinline__ float2 cmulc(float2 a, float2 b) {  // a * conj(b)
    return make_float2(a.x*b.x + a.y*b.y, a.y*b.x - a.x*b.y);
}

// Radix-2 Stockham autosort FFT, 2048 points, NT threads.
// SIGN=-1: forward DFT; SIGN=+1: inverse (unscaled).
// Twiddles via native v_sin/v_cos (args are exact multiples of 2pi/2048).
template<int SIGN, int NT>
__device__ float2* fft2048(float2* bufA, float2* bufB, int tid) {
    float2* src = bufA;
    float2* dst = bufB;
    int m = 1;
    for (int stage = 0; stage < 11; ++stage) {
        __syncthreads();
        #pragma unroll
        for (int it = 0; it < 1024 / NT; ++it) {
            int q = tid + it * NT;
            int k = q & (m - 1);
            int jm = q - k;                 // j*m, twiddle index
            float ang = (float)(SIGN * jm) * 3.0679615757712823e-03f; // 2*pi/2048
            float sv = __sinf(ang);
            float cv = __cosf(ang);
            float2 a = src[q];
            float2 b = src[q + 1024];
            float2 dif = make_float2(a.x - b.x, a.y - b.y);
            dst[2*jm + k]     = make_float2(a.x + b.x, a.y + b.y);
            dst[2*jm + k + m] = make_float2(dif.x*cv - dif.y*sv, dif.x*sv + dif.y*cv);
        }
        float2* t = src; src = dst; dst = t;
        m <<= 1;
    }
    __syncthreads();
    return src;   // 11 stages (odd) -> result in bufB
}

__global__ __launch_bounds__(512) void fft_fwd_kernel(const float* __restrict__ xr,
                                                      const float* __restrict__ xi,
                                                      float2* __restrict__ xf) {
    __shared__ float2 bufA[L_FFT];
    __shared__ float2 bufB[L_FFT];
    int bn = blockIdx.x;            // b*2 + n
    int b = bn >> 1, n = bn & 1;
    int tid = threadIdx.x;
    for (int t = tid; t < L_FFT; t += 512) {
        int gi = (b * L_FFT + t) * NM + n;
        bufA[t] = make_float2(xr[gi], xi[gi]);
    }
    float2* res = fft2048<-1, 512>(bufA, bufB, tid);
    for (int f = tid; f < L_FFT; f += 512)
        xf[bn * L_FFT + f] = res[f];
}

// Fused G + S2. One block per (b, d, l-tile of 256).
// Recomputes the needed 295-entry G slice in LDS from a 336-entry xf slab.
__global__ __launch_bounds__(256) void gs2_kernel(const float2* __restrict__ xf,
                                                  const float* __restrict__ wr,
                                                  const float* __restrict__ wi,
                                                  float2* __restrict__ S2) {
    __shared__ float2 xs[2][336];
    __shared__ float2 Gs[296];
    __shared__ float wrs[40], wis[40];
    int blk = blockIdx.x;
    int b   = blk / 320;
    int rem = blk % 320;
    int d   = rem >> 3;          // n2 index, 0..39
    int l0  = (rem & 7) << 8;    // l-tile origin
    int dd  = d - 20;
    int tid = threadIdx.x;
    const float2* x0 = xf + (b * 2 + 0) * L_FFT;
    const float2* x1 = xf + (b * 2 + 1) * L_FFT;
    for (int i = tid; i < 336; i += 256) {
        int m = (l0 - 39 + i) & (L_FFT - 1);
        xs[0][i] = x0[m];
        xs[1][i] = x1[m];
    }
    if (tid < 40) { wrs[tid] = wr[tid * 40 + d]; wis[tid] = wi[tid * 40 + d]; }
    __syncthreads();
    // Gs[j] = G[b, l0-19+j, d], j in [0,295)
    for (int j = tid; j < 295; j += 256) {
        float2 g0 = cmulc(xs[0][j + 20], xs[0][j + 20 - dd]);
        float2 g1 = cmulc(xs[1][j + 20], xs[1][j + 20 - dd]);
        Gs[j] = make_float2(g0.x + g1.x, g0.y + g1.y);
    }
    __syncthreads();
    // S2[l0+tid] = sum_{n1i} w[n1i,d] * G[l - (n1i-20)]  -> Gs[tid + 39 - n1i]
    float2 acc = make_float2(0.f, 0.f);
    #pragma unroll
    for (int n1i = 0; n1i < 40; ++n1i) {
        float2 g = Gs[tid + 39 - n1i];
        float wxr = wrs[n1i], wxi = wis[n1i];
        acc.x += wxr * g.x - wxi * g.y;
        acc.y += wxr * g.y + wxi * g.x;
    }
    S2[(b * ND + d) * L_FFT + l0 + tid] = acc;
}

// Fused deltaf + inverse FFT + epilogue. One block per (b,n).
__global__ __launch_bounds__(512) void dfifft_kernel(const float2* __restrict__ S2,
                                                     const float2* __restrict__ xf,
                                                     const float* __restrict__ xr,
                                                     const float* __restrict__ xi,
                                                     const float* __restrict__ task,
                                                     float* __restrict__ out) {
    __shared__ float2 xs[L_FFT];
    __shared__ float2 bufA[L_FFT];
    __shared__ float2 bufB[L_FFT];
    int bn = blockIdx.x;            // b*2 + n
    int b = bn >> 1, n = bn & 1;
    int tid = threadIdx.x;
    for (int i = tid; i < L_FFT; i += 512)
        xs[i] = xf[bn * L_FFT + i];
    __syncthreads();
    #pragma unroll
    for (int it = 0; it < 4; ++it) {
        int l = tid + it * 512;
        float2 acc = make_float2(0.f, 0.f);
        for (int d = 0; d < ND; ++d) {
            float2 s  = S2[(b * ND + d) * L_FFT + l];
            float2 xv = xs[(l - (d - 20)) & (L_FFT - 1)];
            acc.x += s.x * xv.x - s.y * xv.y;
            acc.y += s.x * xv.y + s.y * xv.x;
        }
        bufA[l] = acc;
    }
    // fft2048 syncs before its first stage, covering the bufA writes above.
    float2* res = fft2048<1, 512>(bufA, bufB, tid);
    float P = 1e-3f * __powf(10.f, task[b * 4] * 0.1f) * 0.5f;   // /N with N=2
    float scale = P * (1.0f / (float)L_FFT);                     // fold ifft 1/L
    for (int t = CROP + tid; t < L_FFT - CROP; t += 512) {
        int gi = (b * L_FFT + t) * NM + n;
        float2 dv = res[t];
        int oi = ((b * LOUT + (t - CROP)) * NM + n) * 2;
        out[oi]     = xr[gi] + dv.x * scale;
        out[oi + 1] = xi[gi] + dv.y * scale;
    }
}

extern "C" void kernel_launch(void* const* d_in, const int* in_sizes, int n_in,
                              void* d_out, int out_size, void* d_ws, size_t ws_size,
                              hipStream_t stream) {
    const float* xr   = (const float*)d_in[0];
    const float* xi   = (const float*)d_in[1];
    const float* task = (const float*)d_in[2];
    const float* wr   = (const float*)d_in[3];
    const float* wi   = (const float*)d_in[4];
    // d_in[5], d_in[6]: fc_br / fc_bi -- bias lands only at t=0 after IFFT, cropped out.
    float* out = (float*)d_out;

    float2* ws = (float2*)d_ws;
    float2* xf = ws;             // 8192 float2   [b*2+n][l]
    float2* S2 = ws + 8192;      // 163840 float2 [b][d][l]

    hipLaunchKernelGGL(fft_fwd_kernel, dim3(NB * NM), dim3(512), 0, stream, xr, xi, xf);
    hipLaunchKernelGGL(gs2_kernel,     dim3(NB * ND * 8), dim3(256), 0, stream, xf, wr, wi, S2);
    hipLaunchKernelGGL(dfifft_kernel,  dim3(NB * NM), dim3(512), 0, stream, S2, xf, xr, xi, task, out);
}

// Round 3
// 22.733 us; speedup vs baseline: 1.6767x; 1.3616x over previous
//
#include <hip/hip_runtime.h>

// EqFrePBC: frequency-domain perturbation compensation.
// B=2, L=2048, N=2 modes, pairs = full 40x40 grid (n1,n2 in [-20,19]).
//   G[b,m,d]   = sum_n xf[b,m,n]*conj(xf[b,(m-(d-20))%L,n])
//   S2[b,d,l]  = sum_{n1i} w[n1i,d] * G[b,(l-(n1i-20))%L,d]
//   dfreq[b,n,l]= sum_d S2[b,d,l] * xf[b,n,(l-(d-20))%L]
// Bias is constant over freq -> IFFT puts it only at t=0, cropped out.
// K1: fwd-FFT (4 blk x 1024) + zero dfreq
// K2: fused G+S2+deltaf-scatter via fp32 atomics (640 blk x 256)
// K3: IFFT + epilogue (4 blk x 1024)
// S2/dfreq d-reduction happens in L2 via unsafeAtomicAdd; S2 never hits global.

#define L_FFT 2048
#define NB 2
#define NM 2
#define ND 40
#define CROP 20
#define LOUT 2008

__device__ __forceinline__ float2 cmul(float2 a, float2 b) {
    return make_float2(a.x*b.x - a.y*b.y, a.x*b.y + a.y*b.x);
}
__device__ __forceinline__ float2 cmulc(float2 a, float2 b) {  // a * conj(b)
    return make_float2(a.x*b.x + a.y*b.y, a.y*b.x - a.x*b.y);
}

// Build twiddle table tw[t] = exp(SIGN * i * 2*pi*t/2048), t in [0,1024).
template<int SIGN, int NT>
__device__ void build_tw(float2* tw, int tid) {
    for (int t = tid; t < 1024; t += NT) {
        float ang = (float)(SIGN * t) * 3.0679615757712823e-03f;  // 2*pi/2048
        tw[t] = make_float2(__cosf(ang), __sinf(ang));
    }
}

// Radix-2 Stockham autosort FFT, 2048 points, NT threads, table twiddles.
template<int NT>
__device__ float2* fft2048(float2* bufA, float2* bufB, const float2* tw, int tid) {
    float2* src = bufA;
    float2* dst = bufB;
    int m = 1;
    for (int stage = 0; stage < 11; ++stage) {
        __syncthreads();
        #pragma unroll
        for (int it = 0; it < 1024 / NT; ++it) {
            int q = tid + it * NT;
            int k = q & (m - 1);
            int jm = q - k;                 // j*m, twiddle index
            float2 w = tw[jm];
            float2 a = src[q];
            float2 b = src[q + 1024];
            float2 dif = make_float2(a.x - b.x, a.y - b.y);
            dst[2*jm + k]     = make_float2(a.x + b.x, a.y + b.y);
            dst[2*jm + k + m] = make_float2(dif.x*w.x - dif.y*w.y, dif.x*w.y + dif.y*w.x);
        }
        float2* t = src; src = dst; dst = t;
        m <<= 1;
    }
    __syncthreads();
    return src;   // 11 stages (odd) -> result lands in bufB
}

__global__ __launch_bounds__(1024) void fft_fwd_kernel(const float* __restrict__ xr,
                                                       const float* __restrict__ xi,
                                                       float2* __restrict__ xf,
                                                       float* __restrict__ df) {
    __shared__ float2 bufA[L_FFT];
    __shared__ float2 bufB[L_FFT];
    __shared__ float2 tw[1024];
    int bn = blockIdx.x;            // b*2 + n
    int b = bn >> 1, n = bn & 1;
    int tid = threadIdx.x;
    // zero this (b,n)'s dfreq slice for K2's atomic accumulation
    #pragma unroll
    for (int i = 0; i < 4; ++i)
        df[bn * (L_FFT * 2) + tid + i * 1024] = 0.f;
    for (int t = tid; t < L_FFT; t += 1024) {
        int gi = (b * L_FFT + t) * NM + n;
        bufA[t] = make_float2(xr[gi], xi[gi]);
    }
    build_tw<-1, 1024>(tw, tid);
    float2* res = fft2048<1024>(bufA, bufB, tw, tid);   // tw carries the sign
    for (int f = tid; f < L_FFT; f += 1024)
        xf[bn * L_FFT + f] = res[f];
}

// Fused G + S2 + deltaf-scatter. One block per (b, d, l-tile of 256).
__global__ __launch_bounds__(256) void gs2_kernel(const float2* __restrict__ xf,
                                                  const float* __restrict__ wr,
                                                  const float* __restrict__ wi,
                                                  float* __restrict__ df) {
    __shared__ float2 xs[2][336];
    __shared__ float2 Gs[296];
    __shared__ float wrs[40], wis[40];
    int blk = blockIdx.x;
    int b   = blk / 320;
    int rem = blk % 320;
    int d   = rem >> 3;          // n2 index, 0..39
    int l0  = (rem & 7) << 8;    // l-tile origin
    int dd  = d - 20;
    int tid = threadIdx.x;
    const float2* x0 = xf + (b * 2 + 0) * L_FFT;
    const float2* x1 = xf + (b * 2 + 1) * L_FFT;
    for (int i = tid; i < 336; i += 256) {
        int m = (l0 - 39 + i) & (L_FFT - 1);
        xs[0][i] = x0[m];
        xs[1][i] = x1[m];
    }
    if (tid < 40) { wrs[tid] = wr[tid * 40 + d]; wis[tid] = wi[tid * 40 + d]; }
    __syncthreads();
    // Gs[j] = G[b, l0-19+j, d], j in [0,295)
    for (int j = tid; j < 295; j += 256) {
        float2 g0 = cmulc(xs[0][j + 20], xs[0][j + 20 - dd]);
        float2 g1 = cmulc(xs[1][j + 20], xs[1][j + 20 - dd]);
        Gs[j] = make_float2(g0.x + g1.x, g0.y + g1.y);
    }
    __syncthreads();
    // S2[l] = sum_{n1i} w[n1i,d] * G[l-(n1i-20)]  -> Gs[tid + 39 - n1i]
    float2 acc = make_float2(0.f, 0.f);
    #pragma unroll
    for (int n1i = 0; n1i < 40; ++n1i) {
        float2 g = Gs[tid + 39 - n1i];
        float wxr = wrs[n1i], wxi = wis[n1i];
        acc.x += wxr * g.x - wxi * g.y;
        acc.y += wxr * g.y + wxi * g.x;
    }
    // deltaf scatter: df[b,n,l] += S2 * xf[b,n,l-dd]; xf[b,n,l-dd] = xs[n][tid+39-dd]
    int xvi = tid + 39 - dd;
    int base = (b * 2) * (L_FFT * 2) + (l0 + tid) * 2;
    float2 xv0 = xs[0][xvi];
    float2 c0 = cmul(acc, xv0);
    unsafeAtomicAdd(&df[base + 0], c0.x);
    unsafeAtomicAdd(&df[base + 1], c0.y);
    float2 xv1 = xs[1][xvi];
    float2 c1 = cmul(acc, xv1);
    unsafeAtomicAdd(&df[base + L_FFT * 2 + 0], c1.x);
    unsafeAtomicAdd(&df[base + L_FFT * 2 + 1], c1.y);
}

// IFFT + epilogue. One block per (b,n).
__global__ __launch_bounds__(1024) void ifft_out_kernel(const float* __restrict__ df,
                                                        const float* __restrict__ xr,
                                                        const float* __restrict__ xi,
                                                        const float* __restrict__ task,
                                                        float* __restrict__ out) {
    __shared__ float2 bufA[L_FFT];
    __shared__ float2 bufB[L_FFT];
    __shared__ float2 tw[1024];
    int bn = blockIdx.x;            // b*2 + n
    int b = bn >> 1, n = bn & 1;
    int tid = threadIdx.x;
    const float2* dfreq = (const float2*)df + bn * L_FFT;
    for (int i = tid; i < L_FFT; i += 1024)
        bufA[i] = dfreq[i];
    build_tw<1, 1024>(tw, tid);
    float2* res = fft2048<1024>(bufA, bufB, tw, tid);
    float P = 1e-3f * __powf(10.f, task[b * 4] * 0.1f) * 0.5f;   // /N with N=2
    float scale = P * (1.0f / (float)L_FFT);                     // fold ifft 1/L
    for (int t = CROP + tid; t < L_FFT - CROP; t += 1024) {
        int gi = (b * L_FFT + t) * NM + n;
        float2 dv = res[t];
        int oi = ((b * LOUT + (t - CROP)) * NM + n) * 2;
        out[oi]     = xr[gi] + dv.x * scale;
        out[oi + 1] = xi[gi] + dv.y * scale;
    }
}

extern "C" void kernel_launch(void* const* d_in, const int* in_sizes, int n_in,
                              void* d_out, int out_size, void* d_ws, size_t ws_size,
                              hipStream_t stream) {
    const float* xr   = (const float*)d_in[0];
    const float* xi   = (const float*)d_in[1];
    const float* task = (const float*)d_in[2];
    const float* wr   = (const float*)d_in[3];
    const float* wi   = (const float*)d_in[4];
    // d_in[5], d_in[6]: fc_br / fc_bi -- bias lands only at t=0 after IFFT, cropped out.
    float* out = (float*)d_out;

    float2* ws = (float2*)d_ws;
    float2* xf = ws;                    // 8192 float2  [b*2+n][l]
    float*  df = (float*)(ws + 8192);   // 16384 float  [b*2+n][l][2], atomic-accumulated

    hipLaunchKernelGGL(fft_fwd_kernel, dim3(NB * NM), dim3(1024), 0, stream, xr, xi, xf, df);
    hipLaunchKernelGGL(gs2_kernel,     dim3(NB * ND * 8), dim3(256), 0, stream, xf, wr, wi, df);
    hipLaunchKernelGGL(ifft_out_kernel, dim3(NB * NM), dim3(1024), 0, stream, df, xr, xi, task, out);
}